// Round 11
// baseline (342.536 us; speedup 1.0000x reference)
//
#include <hip/hip_runtime.h>
#include <hip/hip_bf16.h>

// L=2048, E=512, E_PT=300, H=16. All inputs f32. Output f32 [2048,512].
//
// R11 = R10 with the diagonal-block double-add FIXED:
// R10's atomic split-K mirrored per-element (gc > gr0+p); diagonal blocks
// (row0==col0) compute BOTH (i,j) and (j,i) directly, so the mirror atomicAdd
// double-counted the sub-diagonal band (|i-j|<64) -> absmax 7.9e-3.
// Fix: mirror only strictly-upper blocks (col0 > row0). Two atomic adds per
// element commute bitwise in IEEE -> S stays exactly symmetric.

typedef __attribute__((ext_vector_type(8))) short bf16x8;
typedef __attribute__((ext_vector_type(4))) float f32x4;

#define L_DIM 2048
#define EPT 300
#define H_DIM 16
#define KDIM 4800
#define WINDOW 5.5e-4f
#define LIST_CAP 2500000

// ---------------- 1) Y + norms ----------------
__global__ void compute_y_kernel(const float* __restrict__ xpt,
                                 const float* __restrict__ Wpt,
                                 __hip_bfloat16* __restrict__ Y,
                                 float* __restrict__ norms) {
  int gw = (blockIdx.x * 256 + threadIdx.x) >> 6;  // wave id = (i,h) pair
  int lane = threadIdx.x & 63;
  int i = gw >> 4, h = gw & 15;
  const float* x = xpt + i * EPT;
  const float* w = Wpt + h * EPT;
  float v[5];
  float ss = 0.f;
#pragma unroll
  for (int t = 0; t < 5; ++t) {
    int e = lane + 64 * t;
    float val = 0.f;
    if (e < EPT) {
      float we = w[e];
      val = x[e] * we * we;
    }
    v[t] = val;
    ss += val * val;
  }
#pragma unroll
  for (int o = 32; o >= 1; o >>= 1) ss += __shfl_xor(ss, o, 64);
  float n = fmaxf(sqrtf(ss), 1e-12f);
  if (lane == 0) norms[i * H_DIM + h] = n;
  float scale = 0.25f / n;  // 1/(norm*sqrt(H))
#pragma unroll
  for (int t = 0; t < 5; ++t) {
    int e = lane + 64 * t;
    if (e < EPT) Y[(size_t)i * KDIM + h * EPT + e] = __float2bfloat16(v[t] * scale);
  }
}

__global__ void w4_kernel(const float* __restrict__ Wpt, float* __restrict__ w4) {
  int i = blockIdx.x * 256 + threadIdx.x;
  if (i < H_DIM * EPT) {
    float w = Wpt[i];
    float w2 = w * w;
    w4[i] = w2 * w2;
  }
}

// ---------------- 2) bt-GEMM: C = A * B^T ----------------
// A: [M,K] bf16 rm, B: [N,K] bf16 rm. XOR-swizzled LDS, double-buffered.
// SPLITX: gridDim.x folds 2 K-halves (x >= gridDim.x/2 -> upper half).
// ATOMIC: epilogue atomicAdd f32 into zeroed accumulator (split-K combine).
// MIRROR: skip fully-below-diagonal blocks; mirror-write ONLY strictly-upper
// blocks (diagonal blocks compute both sides directly).
template <int BM, int BN, bool RELU, bool OUT_BF16, bool MIRROR, bool SPLITX, bool ATOMIC>
__global__ __launch_bounds__(256) void gemm_bt(const __hip_bfloat16* __restrict__ A,
                                               const __hip_bfloat16* __restrict__ B,
                                               void* __restrict__ Cv, int M, int N, int K) {
  constexpr int WMG = BM / 64;        // wave groups along M (1 or 2)
  constexpr int WNG = 4 / WMG;        // wave groups along N
  constexpr int NC = BN / (16 * WNG); // 16-col frags per wave
  int bx = blockIdx.x;
  int kbeg = 0, kend = K;
  if (SPLITX) {
    const int xhalf = gridDim.x >> 1;
    const int khalf = ((K >> 1) + 63) & ~63;
    if (bx >= xhalf) {
      bx -= xhalf;
      kbeg = khalf;
    } else {
      kend = khalf;
    }
  }
  const int row0 = blockIdx.y * BM, col0 = bx * BN;
  if (MIRROR && col0 + BN <= row0) return;  // fully below diagonal
  const bool do_mirror = MIRROR && (col0 > row0);  // diagonal blocks: NO mirror
  __shared__ __attribute__((aligned(16))) __hip_bfloat16 As[2][BM * 64];
  __shared__ __attribute__((aligned(16))) __hip_bfloat16 Bs[2][BN * 64];
  const int tid = threadIdx.x;
  const int lane = tid & 63;
  const int wave = tid >> 6;
  const int wm = wave / WNG, wn = wave % WNG;
  const int r = lane & 15, q = lane >> 4;
  const int srow = tid >> 3;                       // staging row within 32-row group
  const int schunk = (tid & 7) ^ (srow & 7);       // swizzled source chunk

  f32x4 acc[4][NC];
#pragma unroll
  for (int a = 0; a < 4; ++a)
#pragma unroll
    for (int b = 0; b < NC; ++b) {
      f32x4 z = {0.f, 0.f, 0.f, 0.f};
      acc[a][b] = z;
    }

  const int niter = (kend - kbeg) >> 6;

#define STAGE(bufi, k0)                                                                       \
  {                                                                                           \
    _Pragma("unroll") for (int it = 0; it < BM / 32; ++it) {                                  \
      __builtin_amdgcn_global_load_lds(                                                       \
          (const __attribute__((address_space(1))) void*)(A + (size_t)(row0 + it * 32 + srow) * K + \
                                                          (k0) + schunk * 8),                 \
          (__attribute__((address_space(3))) void*)(&As[bufi][(it * 256 + tid) * 8]), 16, 0, 0); \
    }                                                                                         \
    _Pragma("unroll") for (int it = 0; it < BN / 32; ++it) {                                  \
      __builtin_amdgcn_global_load_lds(                                                       \
          (const __attribute__((address_space(1))) void*)(B + (size_t)(col0 + it * 32 + srow) * K + \
                                                          (k0) + schunk * 8),                 \
          (__attribute__((address_space(3))) void*)(&Bs[bufi][(it * 256 + tid) * 8]), 16, 0, 0); \
    }                                                                                         \
  }

  STAGE(0, kbeg)
  for (int k = 0; k < niter; ++k) {
    __syncthreads();  // drains stage(k) (vmcnt0) + all reads of buf (k+1)&1
    if (k + 1 < niter) STAGE((k + 1) & 1, kbeg + ((k + 1) << 6))
    const __hip_bfloat16* as = As[k & 1];
    const __hip_bfloat16* bs = Bs[k & 1];
#pragma unroll
    for (int kk = 0; kk < 2; ++kk) {
      const int ch = ((kk * 4 + q) ^ (r & 7)) * 8;  // swizzled read chunk
      bf16x8 af[4], bfr[NC];
#pragma unroll
      for (int t = 0; t < 4; ++t)
        af[t] = *(const bf16x8*)(as + (wm * 64 + t * 16 + r) * 64 + ch);
#pragma unroll
      for (int c = 0; c < NC; ++c)
        bfr[c] = *(const bf16x8*)(bs + (wn * 16 * NC + c * 16 + r) * 64 + ch);
#pragma unroll
      for (int tm = 0; tm < 4; ++tm)
#pragma unroll
        for (int tn = 0; tn < NC; ++tn)
          acc[tm][tn] = __builtin_amdgcn_mfma_f32_16x16x32_bf16(af[tm], bfr[tn], acc[tm][tn], 0, 0, 0);
    }
  }
#undef STAGE
  // C/D layout: col = lane&15, row = (lane>>4)*4 + reg   [guide §3, m89-verified]
#pragma unroll
  for (int tm = 0; tm < 4; ++tm) {
    int gr0 = row0 + wm * 64 + tm * 16 + q * 4;
#pragma unroll
    for (int tn = 0; tn < NC; ++tn) {
      int gc = col0 + wn * 16 * NC + tn * 16 + r;
#pragma unroll
      for (int p = 0; p < 4; ++p) {
        float vv = acc[tm][tn][p];
        if (RELU) vv = fmaxf(vv, 0.f);
        if (ATOMIC) {
          atomicAdd(&((float*)Cv)[(size_t)(gr0 + p) * N + gc], vv);
          if (do_mirror) atomicAdd(&((float*)Cv)[(size_t)gc * N + (gr0 + p)], vv);
        } else if (OUT_BF16) {
          ((__hip_bfloat16*)Cv)[(size_t)(gr0 + p) * N + gc] = __float2bfloat16(vv);
        } else {
          ((float*)Cv)[(size_t)(gr0 + p) * N + gc] = vv;
          if (do_mirror) ((float*)Cv)[(size_t)gc * N + (gr0 + p)] = vv;
        }
      }
    }
  }
}

// ---------------- 3a) scan upper triangle, per-block LDS compaction ----------
__global__ __launch_bounds__(256) void scan_borderline(const float* __restrict__ S,
                                                       int* __restrict__ count,
                                                       int* __restrict__ list) {
  __shared__ int lqueue[2048];
  __shared__ int lcount;
  __shared__ int gbase;
  if (threadIdx.x == 0) lcount = 0;
  __syncthreads();
  const int row = blockIdx.x;
  const int base_idx = row * 2048;
#pragma unroll
  for (int t = 0; t < 2; ++t) {
    int idx = base_idx + t * 1024 + threadIdx.x * 4;
    float4 v = *(const float4*)(S + idx);
    float vv[4] = {v.x, v.y, v.z, v.w};
#pragma unroll
    for (int u = 0; u < 4; ++u) {
      int j = (idx + u) & 2047;
      if (j >= row && fabsf(vv[u] - 0.1f) < WINDOW) {
        int p = atomicAdd(&lcount, 1);  // LDS atomic
        lqueue[p] = idx + u;
      }
    }
  }
  __syncthreads();
  if (threadIdx.x == 0) gbase = atomicAdd(count, lcount);
  __syncthreads();
  int n = lcount, g0 = gbase;
  for (int k = threadIdx.x; k < n; k += 256) {
    int pos = g0 + k;
    if (pos < LIST_CAP) list[pos] = lqueue[k];
  }
}

// ---------------- 3b) exact f32 repair, pipelined xj prefetch ----------------
__global__ void repair_borderline(float* __restrict__ S, const int* __restrict__ count,
                                  const int* __restrict__ list, const float* __restrict__ xpt,
                                  const float* __restrict__ w4, const float* __restrict__ norms) {
  const int lane = threadIdx.x & 63;
  const int wid = (blockIdx.x * 256 + threadIdx.x) >> 6;
  const int nw = gridDim.x * 4;
  int n = *count;
  if (n > LIST_CAP) n = LIST_CAP;
  const int chunk = (n + nw - 1) / nw;
  int k0 = wid * chunk;
  int k1 = k0 + chunk < n ? k0 + chunk : n;
  if (k0 >= k1) return;
  int e = list[k0];
  int i = e >> 11, j = e & 2047;
  float xiv[5], xjv[5];
  {
    const float* xi = xpt + i * EPT;
    const float* xj = xpt + j * EPT;
#pragma unroll
    for (int t = 0; t < 5; ++t) {
      int idx = lane + 64 * t;
      xiv[t] = idx < EPT ? xi[idx] : 0.f;
      xjv[t] = idx < EPT ? xj[idx] : 0.f;
    }
  }
  int cur_i = i;
  for (int k = k0; k < k1; ++k) {
    int en = (k + 1 < k1) ? list[k + 1] : e;
    int in2 = en >> 11, jn = en & 2047;
    const float* xjp = xpt + jn * EPT;
    float xjn[5];
#pragma unroll
    for (int t = 0; t < 5; ++t) {
      int idx = lane + 64 * t;
      xjn[t] = idx < EPT ? xjp[idx] : 0.f;
    }
    float pre[5];
#pragma unroll
    for (int t = 0; t < 5; ++t) pre[t] = xiv[t] * xjv[t];
    float accv = 0.f;
#pragma unroll
    for (int h = 0; h < H_DIM; ++h) {
      float ph = 0.f;
#pragma unroll
      for (int t = 0; t < 5; ++t) {
        int idx = lane + 64 * t;
        if (idx < EPT) ph += pre[t] * w4[h * EPT + idx];
      }
      float invn = 1.f / (norms[i * H_DIM + h] * norms[j * H_DIM + h]);
      accv += ph * invn;
    }
#pragma unroll
    for (int o = 32; o >= 1; o >>= 1) accv += __shfl_xor(accv, o, 64);
    if (lane == 0) {
      float val = accv * (1.f / 16.f);
      S[(size_t)i * L_DIM + j] = val;
      S[(size_t)j * L_DIM + i] = val;  // symmetric twin
    }
    if (in2 != cur_i) {
      const float* xi = xpt + in2 * EPT;
#pragma unroll
      for (int t = 0; t < 5; ++t) {
        int idx = lane + 64 * t;
        xiv[t] = idx < EPT ? xi[idx] : 0.f;
      }
      cur_i = in2;
    }
    i = in2;
    j = jn;
    e = en;
#pragma unroll
    for (int t = 0; t < 5; ++t) xjv[t] = xjn[t];
  }
}

// ---------------- 4) thresholded row softmax -> bf16 adj ----------------
__global__ void softmax_kernel(const float* __restrict__ S, __hip_bfloat16* __restrict__ adj) {
  __shared__ float red[4];
  const int row = blockIdx.x;
  const float* s = S + (size_t)row * L_DIM;
  const int tid = threadIdx.x;
  float m = -1e30f;
  for (int j = tid; j < L_DIM; j += 256) {
    float v = s[j];
    if (v >= 0.1f && v > m) m = v;
  }
#pragma unroll
  for (int o = 32; o >= 1; o >>= 1) m = fmaxf(m, __shfl_xor(m, o, 64));
  if ((tid & 63) == 0) red[tid >> 6] = m;
  __syncthreads();
  m = fmaxf(fmaxf(red[0], red[1]), fmaxf(red[2], red[3]));
  float sum = 0.f;
  for (int j = tid; j < L_DIM; j += 256) {
    float v = s[j];
    if (v >= 0.1f) sum += __expf(v - m);
  }
#pragma unroll
  for (int o = 32; o >= 1; o >>= 1) sum += __shfl_xor(sum, o, 64);
  __syncthreads();
  if ((tid & 63) == 0) red[tid >> 6] = sum;
  __syncthreads();
  sum = red[0] + red[1] + red[2] + red[3];
  float inv = 1.f / sum;
  for (int j = tid; j < L_DIM; j += 256) {
    float v = s[j];
    float a = (v >= 0.1f) ? __expf(v - m) * inv : 0.f;
    adj[(size_t)row * L_DIM + j] = __float2bfloat16(a);
  }
}

// ---------------- helpers ----------------
__global__ void cast_bf16_kernel(const float* __restrict__ in, __hip_bfloat16* __restrict__ out,
                                 int n) {
  int i = blockIdx.x * 256 + threadIdx.x;
  if (i < n) out[i] = __float2bfloat16(in[i]);
}

// relu + cast f32 acc -> bf16 (float4-vectorized)
__global__ void relu_cast_bf16_kernel(const float* __restrict__ in,
                                      __hip_bfloat16* __restrict__ out) {
  int i = blockIdx.x * 256 + threadIdx.x;
  float4 a = ((const float4*)in)[i];
  __hip_bfloat16 o0 = __float2bfloat16(fmaxf(a.x, 0.f));
  __hip_bfloat16 o1 = __float2bfloat16(fmaxf(a.y, 0.f));
  __hip_bfloat16 o2 = __float2bfloat16(fmaxf(a.z, 0.f));
  __hip_bfloat16 o3 = __float2bfloat16(fmaxf(a.w, 0.f));
  out[4 * i + 0] = o0;
  out[4 * i + 1] = o1;
  out[4 * i + 2] = o2;
  out[4 * i + 3] = o3;
}

__global__ void relu_f32_kernel(const float* __restrict__ in, float* __restrict__ out) {
  int i = blockIdx.x * 256 + threadIdx.x;
  float4 a = ((const float4*)in)[i];
  float4 v;
  v.x = fmaxf(a.x, 0.f);
  v.y = fmaxf(a.y, 0.f);
  v.z = fmaxf(a.z, 0.f);
  v.w = fmaxf(a.w, 0.f);
  ((float4*)out)[i] = v;
}

template <typename T>
__global__ void transpose_bf16_kernel(const T* __restrict__ in, __hip_bfloat16* __restrict__ out,
                                      int R, int C) {
  __shared__ float tile[32][33];
  int c0 = blockIdx.x * 32, r0 = blockIdx.y * 32;
  int tx = threadIdx.x, ty = threadIdx.y;
  for (int i = ty; i < 32; i += 8) tile[i][tx] = (float)in[(size_t)(r0 + i) * C + c0 + tx];
  __syncthreads();
  for (int i = ty; i < 32; i += 8)
    out[(size_t)(c0 + i) * R + r0 + tx] = __float2bfloat16(tile[tx][i]);
}

extern "C" void kernel_launch(void* const* d_in, const int* in_sizes, int n_in, void* d_out,
                              int out_size, void* d_ws, size_t ws_size, hipStream_t stream) {
  const float* label = (const float*)d_in[0];  // [2048,512]
  const float* xpt = (const float*)d_in[1];    // [2048,300]
  const float* Wpt = (const float*)d_in[2];    // [16,300]
  const float* W0 = (const float*)d_in[3];     // [512,512]
  const float* W1 = (const float*)d_in[4];     // [512,512]
  float* out = (float*)d_out;                  // [2048,512]

  // ---- layout: identical envelope to R5/R8/R9 (peak 36,588,288 B, proven) ----
  char* ws = (char*)d_ws;
  __hip_bfloat16* Y = (__hip_bfloat16*)ws;              // [0, 19,660,800)
  float* S = (float*)(ws + 19660800);                   // 16,777,216 B
  float* norms = (float*)(ws + 36438016);               // 131,072 B
  float* w4 = (float*)(ws + 36569088);                  // 19,200 B -> end 36,588,288
  int* bl_count = (int*)(ws + 9437184);                 // inside dead Y, above adj
  int* bl_list = (int*)(ws + 9437696);                  // cap 2.5M ints, ends < 19.66MB
  __hip_bfloat16* adj = (__hip_bfloat16*)ws;            // reuses Y region
  char* tmp = ws + 19660800;                            // reuses S region after softmax
  __hip_bfloat16* Lbf = (__hip_bfloat16*)tmp;                 // 2MB
  __hip_bfloat16* W0t = (__hip_bfloat16*)(tmp + 2097152);     // 0.5MB
  __hip_bfloat16* W1t = (__hip_bfloat16*)(tmp + 2621440);     // 0.5MB
  __hip_bfloat16* T0t = (__hip_bfloat16*)(tmp + 3145728);     // 2MB [512x2048]
  __hip_bfloat16* X1 = (__hip_bfloat16*)(tmp + 5242880);      // 2MB [2048x512]
  __hip_bfloat16* T1t = (__hip_bfloat16*)(tmp + 7340032);     // 2MB
  float* ACC = (float*)(tmp + 9437184);                       // 4.19MB f32 acc (X1 then out)
                                                              // ends tmp+13,631,488 < 16.78MB

  compute_y_kernel<<<8192, 256, 0, stream>>>(xpt, Wpt, Y, norms);
  w4_kernel<<<19, 256, 0, stream>>>(Wpt, w4);
  // S = Y Y^T, symmetric, atomic split-K=2: grid(64,32) -> 1056 active blocks
  hipMemsetAsync(S, 0, 16777216, stream);
  gemm_bt<64, 64, false, false, true, true, true><<<dim3(64, 32), 256, 0, stream>>>(Y, Y, S, 2048, 2048, KDIM);
  // borderline: compact (upper-tri, window 5.5e-4) then repair (pipelined)
  hipMemsetAsync(bl_count, 0, 4, stream);
  scan_borderline<<<2048, 256, 0, stream>>>(S, bl_count, bl_list);
  repair_borderline<<<2048, 256, 0, stream>>>(S, bl_count, bl_list, xpt, w4, norms);
  softmax_kernel<<<2048, 256, 0, stream>>>(S, adj);  // adj overwrites Y region (Y dead)
  // GCN prep (S region dead now)
  cast_bf16_kernel<<<4096, 256, 0, stream>>>(label, Lbf, 2048 * 512);
  transpose_bf16_kernel<float><<<dim3(16, 16), dim3(32, 8), 0, stream>>>(W0, W0t, 512, 512);
  transpose_bf16_kernel<float><<<dim3(16, 16), dim3(32, 8), 0, stream>>>(W1, W1t, 512, 512);
  // T0t = (label@W0)^T = W0t * Lbf^T   [512 x 2048]
  gemm_bt<64, 64, false, true, false, false, false><<<dim3(32, 8), 256, 0, stream>>>(W0t, Lbf, T0t, 512, 2048, 512);
  // X1 = relu(adj @ T0): atomic split-K=2 into ACC, then relu-cast
  hipMemsetAsync(ACC, 0, 4194304, stream);
  gemm_bt<64, 64, false, false, false, true, true><<<dim3(16, 32), 256, 0, stream>>>(adj, T0t, ACC, 2048, 512, 2048);
  relu_cast_bf16_kernel<<<1024, 256, 0, stream>>>(ACC, X1);
  // T1t = (X1@W1)^T = W1t * X1^T   [512 x 2048]
  gemm_bt<64, 64, false, true, false, false, false><<<dim3(32, 8), 256, 0, stream>>>(W1t, X1, T1t, 512, 2048, 512);
  // out = relu(adj @ T1): atomic split-K=2 into ACC (reused), then relu
  hipMemsetAsync(ACC, 0, 4194304, stream);
  gemm_bt<64, 64, false, false, false, true, true><<<dim3(16, 32), 256, 0, stream>>>(adj, T1t, ACC, 2048, 512, 2048);
  relu_f32_kernel<<<1024, 256, 0, stream>>>(ACC, out);
}

// Round 12
// 295.217 us; speedup vs baseline: 1.1603x; 1.1603x over previous
//
#include <hip/hip_runtime.h>
#include <hip/hip_bf16.h>

// L=2048, E=512, E_PT=300, H=16. All inputs f32. Output f32 [2048,512].
//
// R12 = R9 (proven 284us) + buffer-based split-K=2 for the gram only:
//  - R11's atomic split-K quintupled WRITE_SIZE (80MB, L2 RMW storm) -> revert.
//  - gram: x-folded grid(64,32) (NO z-dim: R6/R7 crashes correlate with 3D
//    grids under graph capture), half-K plain stores into S and partial P1,
//    mirror only strictly-upper blocks; combine S+=P1 fused into the scan.
//  - P1 costs +16.8MB: gated at runtime on ws_size >= 53,365,504; otherwise
//    exact R9 fallback (single-pass gram + plain scan).
//  - adj-gemms back to R9 non-split (direct RELU+store).

typedef __attribute__((ext_vector_type(8))) short bf16x8;
typedef __attribute__((ext_vector_type(4))) float f32x4;

#define L_DIM 2048
#define EPT 300
#define H_DIM 16
#define KDIM 4800
#define WINDOW 5.5e-4f
#define LIST_CAP 2500000

// ---------------- 1) Y + norms ----------------
__global__ void compute_y_kernel(const float* __restrict__ xpt,
                                 const float* __restrict__ Wpt,
                                 __hip_bfloat16* __restrict__ Y,
                                 float* __restrict__ norms) {
  int gw = (blockIdx.x * 256 + threadIdx.x) >> 6;  // wave id = (i,h) pair
  int lane = threadIdx.x & 63;
  int i = gw >> 4, h = gw & 15;
  const float* x = xpt + i * EPT;
  const float* w = Wpt + h * EPT;
  float v[5];
  float ss = 0.f;
#pragma unroll
  for (int t = 0; t < 5; ++t) {
    int e = lane + 64 * t;
    float val = 0.f;
    if (e < EPT) {
      float we = w[e];
      val = x[e] * we * we;
    }
    v[t] = val;
    ss += val * val;
  }
#pragma unroll
  for (int o = 32; o >= 1; o >>= 1) ss += __shfl_xor(ss, o, 64);
  float n = fmaxf(sqrtf(ss), 1e-12f);
  if (lane == 0) norms[i * H_DIM + h] = n;
  float scale = 0.25f / n;  // 1/(norm*sqrt(H))
#pragma unroll
  for (int t = 0; t < 5; ++t) {
    int e = lane + 64 * t;
    if (e < EPT) Y[(size_t)i * KDIM + h * EPT + e] = __float2bfloat16(v[t] * scale);
  }
}

__global__ void w4_kernel(const float* __restrict__ Wpt, float* __restrict__ w4) {
  int i = blockIdx.x * 256 + threadIdx.x;
  if (i < H_DIM * EPT) {
    float w = Wpt[i];
    float w2 = w * w;
    w4[i] = w2 * w2;
  }
}

// ---------------- 2) bt-GEMM: C = A * B^T ----------------
// A: [M,K] bf16 rm, B: [N,K] bf16 rm. XOR-swizzled LDS, double-buffered.
// SPLITX: gridDim.x folds 2 K-halves; half0 -> C0, half1 -> C1 (plain stores).
// MIRROR: skip fully-below-diagonal blocks; mirror-write only strictly-upper
// blocks (diagonal blocks cover both triangle halves directly).
template <int BM, int BN, bool RELU, bool OUT_BF16, bool MIRROR, bool SPLITX>
__global__ __launch_bounds__(256) void gemm_bt(const __hip_bfloat16* __restrict__ A,
                                               const __hip_bfloat16* __restrict__ B,
                                               void* __restrict__ C0v, void* __restrict__ C1v,
                                               int M, int N, int K) {
  constexpr int WMG = BM / 64;        // wave groups along M (1 or 2)
  constexpr int WNG = 4 / WMG;        // wave groups along N
  constexpr int NC = BN / (16 * WNG); // 16-col frags per wave
  int bx = blockIdx.x;
  int kbeg = 0, kend = K;
  if (SPLITX) {
    const int xhalf = gridDim.x >> 1;
    const int khalf = ((K >> 1) + 63) & ~63;
    if (bx >= xhalf) {
      bx -= xhalf;
      kbeg = khalf;
    } else {
      kend = khalf;
    }
  }
  const int row0 = blockIdx.y * BM, col0 = bx * BN;
  if (MIRROR && col0 + BN <= row0) return;  // fully below diagonal
  const bool do_mirror = MIRROR && (col0 > row0);
  __shared__ __attribute__((aligned(16))) __hip_bfloat16 As[2][BM * 64];
  __shared__ __attribute__((aligned(16))) __hip_bfloat16 Bs[2][BN * 64];
  const int tid = threadIdx.x;
  const int lane = tid & 63;
  const int wave = tid >> 6;
  const int wm = wave / WNG, wn = wave % WNG;
  const int r = lane & 15, q = lane >> 4;
  const int srow = tid >> 3;                       // staging row within 32-row group
  const int schunk = (tid & 7) ^ (srow & 7);       // swizzled source chunk

  f32x4 acc[4][NC];
#pragma unroll
  for (int a = 0; a < 4; ++a)
#pragma unroll
    for (int b = 0; b < NC; ++b) {
      f32x4 z = {0.f, 0.f, 0.f, 0.f};
      acc[a][b] = z;
    }

  const int niter = (kend - kbeg) >> 6;

#define STAGE(bufi, k0)                                                                       \
  {                                                                                           \
    _Pragma("unroll") for (int it = 0; it < BM / 32; ++it) {                                  \
      __builtin_amdgcn_global_load_lds(                                                       \
          (const __attribute__((address_space(1))) void*)(A + (size_t)(row0 + it * 32 + srow) * K + \
                                                          (k0) + schunk * 8),                 \
          (__attribute__((address_space(3))) void*)(&As[bufi][(it * 256 + tid) * 8]), 16, 0, 0); \
    }                                                                                         \
    _Pragma("unroll") for (int it = 0; it < BN / 32; ++it) {                                  \
      __builtin_amdgcn_global_load_lds(                                                       \
          (const __attribute__((address_space(1))) void*)(B + (size_t)(col0 + it * 32 + srow) * K + \
                                                          (k0) + schunk * 8),                 \
          (__attribute__((address_space(3))) void*)(&Bs[bufi][(it * 256 + tid) * 8]), 16, 0, 0); \
    }                                                                                         \
  }

  STAGE(0, kbeg)
  for (int k = 0; k < niter; ++k) {
    __syncthreads();  // drains stage(k) (vmcnt0) + all reads of buf (k+1)&1
    if (k + 1 < niter) STAGE((k + 1) & 1, kbeg + ((k + 1) << 6))
    const __hip_bfloat16* as = As[k & 1];
    const __hip_bfloat16* bs = Bs[k & 1];
#pragma unroll
    for (int kk = 0; kk < 2; ++kk) {
      const int ch = ((kk * 4 + q) ^ (r & 7)) * 8;  // swizzled read chunk
      bf16x8 af[4], bfr[NC];
#pragma unroll
      for (int t = 0; t < 4; ++t)
        af[t] = *(const bf16x8*)(as + (wm * 64 + t * 16 + r) * 64 + ch);
#pragma unroll
      for (int c = 0; c < NC; ++c)
        bfr[c] = *(const bf16x8*)(bs + (wn * 16 * NC + c * 16 + r) * 64 + ch);
#pragma unroll
      for (int tm = 0; tm < 4; ++tm)
#pragma unroll
        for (int tn = 0; tn < NC; ++tn)
          acc[tm][tn] = __builtin_amdgcn_mfma_f32_16x16x32_bf16(af[tm], bfr[tn], acc[tm][tn], 0, 0, 0);
    }
  }
#undef STAGE
  float* dst = (float*)(SPLITX ? (kbeg > 0 ? C1v : C0v) : C0v);
  // C/D layout: col = lane&15, row = (lane>>4)*4 + reg   [guide §3, m89-verified]
#pragma unroll
  for (int tm = 0; tm < 4; ++tm) {
    int gr0 = row0 + wm * 64 + tm * 16 + q * 4;
#pragma unroll
    for (int tn = 0; tn < NC; ++tn) {
      int gc = col0 + wn * 16 * NC + tn * 16 + r;
#pragma unroll
      for (int p = 0; p < 4; ++p) {
        float vv = acc[tm][tn][p];
        if (RELU) vv = fmaxf(vv, 0.f);
        if (OUT_BF16) {
          ((__hip_bfloat16*)C0v)[(size_t)(gr0 + p) * N + gc] = __float2bfloat16(vv);
        } else {
          dst[(size_t)(gr0 + p) * N + gc] = vv;
          if (do_mirror) dst[(size_t)gc * N + (gr0 + p)] = vv;
        }
      }
    }
  }
}

// ---------------- 3a) scan upper triangle (optionally fused S += P1) --------
template <bool COMBINE>
__global__ __launch_bounds__(256) void scan_borderline(float* __restrict__ S,
                                                       const float* __restrict__ P1,
                                                       int* __restrict__ count,
                                                       int* __restrict__ list) {
  __shared__ int lqueue[2048];
  __shared__ int lcount;
  __shared__ int gbase;
  if (threadIdx.x == 0) lcount = 0;
  __syncthreads();
  const int row = blockIdx.x;
  const int base_idx = row * 2048;
#pragma unroll
  for (int t = 0; t < 2; ++t) {
    int idx = base_idx + t * 1024 + threadIdx.x * 4;
    float4 v = *(const float4*)(S + idx);
    if (COMBINE) {
      float4 b = *(const float4*)(P1 + idx);
      v.x += b.x; v.y += b.y; v.z += b.z; v.w += b.w;
      *(float4*)(S + idx) = v;
    }
    float vv[4] = {v.x, v.y, v.z, v.w};
#pragma unroll
    for (int u = 0; u < 4; ++u) {
      int j = (idx + u) & 2047;
      if (j >= row && fabsf(vv[u] - 0.1f) < WINDOW) {
        int p = atomicAdd(&lcount, 1);  // LDS atomic
        lqueue[p] = idx + u;
      }
    }
  }
  __syncthreads();
  if (threadIdx.x == 0) gbase = atomicAdd(count, lcount);
  __syncthreads();
  int n = lcount, g0 = gbase;
  for (int k = threadIdx.x; k < n; k += 256) {
    int pos = g0 + k;
    if (pos < LIST_CAP) list[pos] = lqueue[k];
  }
}

// ---------------- 3b) exact f32 repair, pipelined xj prefetch ----------------
__global__ void repair_borderline(float* __restrict__ S, const int* __restrict__ count,
                                  const int* __restrict__ list, const float* __restrict__ xpt,
                                  const float* __restrict__ w4, const float* __restrict__ norms) {
  const int lane = threadIdx.x & 63;
  const int wid = (blockIdx.x * 256 + threadIdx.x) >> 6;
  const int nw = gridDim.x * 4;
  int n = *count;
  if (n > LIST_CAP) n = LIST_CAP;
  const int chunk = (n + nw - 1) / nw;
  int k0 = wid * chunk;
  int k1 = k0 + chunk < n ? k0 + chunk : n;
  if (k0 >= k1) return;
  int e = list[k0];
  int i = e >> 11, j = e & 2047;
  float xiv[5], xjv[5];
  {
    const float* xi = xpt + i * EPT;
    const float* xj = xpt + j * EPT;
#pragma unroll
    for (int t = 0; t < 5; ++t) {
      int idx = lane + 64 * t;
      xiv[t] = idx < EPT ? xi[idx] : 0.f;
      xjv[t] = idx < EPT ? xj[idx] : 0.f;
    }
  }
  int cur_i = i;
  for (int k = k0; k < k1; ++k) {
    int en = (k + 1 < k1) ? list[k + 1] : e;
    int in2 = en >> 11, jn = en & 2047;
    const float* xjp = xpt + jn * EPT;
    float xjn[5];
#pragma unroll
    for (int t = 0; t < 5; ++t) {
      int idx = lane + 64 * t;
      xjn[t] = idx < EPT ? xjp[idx] : 0.f;
    }
    float pre[5];
#pragma unroll
    for (int t = 0; t < 5; ++t) pre[t] = xiv[t] * xjv[t];
    float accv = 0.f;
#pragma unroll
    for (int h = 0; h < H_DIM; ++h) {
      float ph = 0.f;
#pragma unroll
      for (int t = 0; t < 5; ++t) {
        int idx = lane + 64 * t;
        if (idx < EPT) ph += pre[t] * w4[h * EPT + idx];
      }
      float invn = 1.f / (norms[i * H_DIM + h] * norms[j * H_DIM + h]);
      accv += ph * invn;
    }
#pragma unroll
    for (int o = 32; o >= 1; o >>= 1) accv += __shfl_xor(accv, o, 64);
    if (lane == 0) {
      float val = accv * (1.f / 16.f);
      S[(size_t)i * L_DIM + j] = val;
      S[(size_t)j * L_DIM + i] = val;  // symmetric twin
    }
    if (in2 != cur_i) {
      const float* xi = xpt + in2 * EPT;
#pragma unroll
      for (int t = 0; t < 5; ++t) {
        int idx = lane + 64 * t;
        xiv[t] = idx < EPT ? xi[idx] : 0.f;
      }
      cur_i = in2;
    }
    i = in2;
    j = jn;
    e = en;
#pragma unroll
    for (int t = 0; t < 5; ++t) xjv[t] = xjn[t];
  }
}

// ---------------- 4) thresholded row softmax -> bf16 adj ----------------
__global__ void softmax_kernel(const float* __restrict__ S, __hip_bfloat16* __restrict__ adj) {
  __shared__ float red[4];
  const int row = blockIdx.x;
  const float* s = S + (size_t)row * L_DIM;
  const int tid = threadIdx.x;
  float m = -1e30f;
  for (int j = tid; j < L_DIM; j += 256) {
    float v = s[j];
    if (v >= 0.1f && v > m) m = v;
  }
#pragma unroll
  for (int o = 32; o >= 1; o >>= 1) m = fmaxf(m, __shfl_xor(m, o, 64));
  if ((tid & 63) == 0) red[tid >> 6] = m;
  __syncthreads();
  m = fmaxf(fmaxf(red[0], red[1]), fmaxf(red[2], red[3]));
  float sum = 0.f;
  for (int j = tid; j < L_DIM; j += 256) {
    float v = s[j];
    if (v >= 0.1f) sum += __expf(v - m);
  }
#pragma unroll
  for (int o = 32; o >= 1; o >>= 1) sum += __shfl_xor(sum, o, 64);
  __syncthreads();
  if ((tid & 63) == 0) red[tid >> 6] = sum;
  __syncthreads();
  sum = red[0] + red[1] + red[2] + red[3];
  float inv = 1.f / sum;
  for (int j = tid; j < L_DIM; j += 256) {
    float v = s[j];
    float a = (v >= 0.1f) ? __expf(v - m) * inv : 0.f;
    adj[(size_t)row * L_DIM + j] = __float2bfloat16(a);
  }
}

// ---------------- helpers ----------------
__global__ void cast_bf16_kernel(const float* __restrict__ in, __hip_bfloat16* __restrict__ out,
                                 int n) {
  int i = blockIdx.x * 256 + threadIdx.x;
  if (i < n) out[i] = __float2bfloat16(in[i]);
}

template <typename T>
__global__ void transpose_bf16_kernel(const T* __restrict__ in, __hip_bfloat16* __restrict__ out,
                                      int R, int C) {
  __shared__ float tile[32][33];
  int c0 = blockIdx.x * 32, r0 = blockIdx.y * 32;
  int tx = threadIdx.x, ty = threadIdx.y;
  for (int i = ty; i < 32; i += 8) tile[i][tx] = (float)in[(size_t)(r0 + i) * C + c0 + tx];
  __syncthreads();
  for (int i = ty; i < 32; i += 8)
    out[(size_t)(c0 + i) * R + r0 + tx] = __float2bfloat16(tile[tx][i]);
}

extern "C" void kernel_launch(void* const* d_in, const int* in_sizes, int n_in, void* d_out,
                              int out_size, void* d_ws, size_t ws_size, hipStream_t stream) {
  const float* label = (const float*)d_in[0];  // [2048,512]
  const float* xpt = (const float*)d_in[1];    // [2048,300]
  const float* Wpt = (const float*)d_in[2];    // [16,300]
  const float* W0 = (const float*)d_in[3];     // [512,512]
  const float* W1 = (const float*)d_in[4];     // [512,512]
  float* out = (float*)d_out;                  // [2048,512]

  char* ws = (char*)d_ws;
  __hip_bfloat16* Y = (__hip_bfloat16*)ws;              // [0, 19,660,800)
  float* S = (float*)(ws + 19660800);                   // 16,777,216 B
  int* bl_count = (int*)(ws + 9437184);                 // inside dead Y, above adj
  int* bl_list = (int*)(ws + 9437696);                  // cap 2.5M ints, ends < 19.66MB
  __hip_bfloat16* adj = (__hip_bfloat16*)ws;            // reuses Y region
  char* tmp = ws + 19660800;                            // reuses S region after softmax
  __hip_bfloat16* Lbf = (__hip_bfloat16*)tmp;                 // 2MB
  __hip_bfloat16* W0t = (__hip_bfloat16*)(tmp + 2097152);     // 0.5MB
  __hip_bfloat16* W1t = (__hip_bfloat16*)(tmp + 2621440);     // 0.5MB
  __hip_bfloat16* T0t = (__hip_bfloat16*)(tmp + 3145728);     // 2MB [512x2048]
  __hip_bfloat16* X1 = (__hip_bfloat16*)(tmp + 5242880);      // 2MB [2048x512]
  __hip_bfloat16* T1t = (__hip_bfloat16*)(tmp + 7340032);     // 2MB -> tmp end 9,437,184

  // split-K gram needs P1 (16.78MB) after S; norms/w4 slide up accordingly.
  const size_t SPLIT_REQ = 36438016ull + 16777216ull + 131072ull + 19200ull;  // 53,365,504
  const bool use_split = ws_size >= SPLIT_REQ;
  float* P1 = (float*)(ws + 36438016);
  float* norms = use_split ? (float*)(ws + 53215232) : (float*)(ws + 36438016);
  float* w4 = use_split ? (float*)(ws + 53346304) : (float*)(ws + 36569088);

  compute_y_kernel<<<8192, 256, 0, stream>>>(xpt, Wpt, Y, norms);
  w4_kernel<<<19, 256, 0, stream>>>(Wpt, w4);
  hipMemsetAsync(bl_count, 0, 4, stream);
  if (use_split) {
    // gram split-K=2 (x-folded, no z-dim): half0 -> S, half1 -> P1; 1056 blocks
    gemm_bt<64, 64, false, false, true, true><<<dim3(64, 32), 256, 0, stream>>>(Y, Y, S, P1, 2048, 2048, KDIM);
    // combine S += P1 fused into the borderline scan
    scan_borderline<true><<<2048, 256, 0, stream>>>(S, P1, bl_count, bl_list);
  } else {
    // R9 fallback: single-pass triangle gram + plain scan
    gemm_bt<64, 64, false, false, true, false><<<dim3(32, 32), 256, 0, stream>>>(Y, Y, S, nullptr, 2048, 2048, KDIM);
    scan_borderline<false><<<2048, 256, 0, stream>>>(S, nullptr, bl_count, bl_list);
  }
  repair_borderline<<<2048, 256, 0, stream>>>(S, bl_count, bl_list, xpt, w4, norms);
  softmax_kernel<<<2048, 256, 0, stream>>>(S, adj);  // adj overwrites Y region (Y dead)
  // GCN prep (S region dead now)
  cast_bf16_kernel<<<4096, 256, 0, stream>>>(label, Lbf, 2048 * 512);
  transpose_bf16_kernel<float><<<dim3(16, 16), dim3(32, 8), 0, stream>>>(W0, W0t, 512, 512);
  transpose_bf16_kernel<float><<<dim3(16, 16), dim3(32, 8), 0, stream>>>(W1, W1t, 512, 512);
  // T0t = (label@W0)^T = W0t * Lbf^T   [512 x 2048]
  gemm_bt<64, 64, false, true, false, false><<<dim3(32, 8), 256, 0, stream>>>(W0t, Lbf, T0t, nullptr, 512, 2048, 512);
  // X1 = relu(adj @ T0) = relu(adj * T0t^T)   [2048 x 512] bf16
  gemm_bt<64, 64, true, true, false, false><<<dim3(8, 32), 256, 0, stream>>>(adj, T0t, X1, nullptr, 2048, 512, 2048);
  // T1t = (X1@W1)^T = W1t * X1^T   [512 x 2048]
  gemm_bt<64, 64, false, true, false, false><<<dim3(32, 8), 256, 0, stream>>>(W1t, X1, T1t, nullptr, 512, 2048, 512);
  // out = relu(adj @ T1) = relu(adj * T1t^T)   [2048 x 512] f32
  gemm_bt<64, 64, true, false, false, false><<<dim3(8, 32), 256, 0, stream>>>(adj, T1t, out, nullptr, 2048, 512, 2048);
}